// Round 14
// baseline (445.817 us; speedup 1.0000x reference)
//
#include <hip/hip_runtime.h>

typedef __bf16 bf16x8 __attribute__((ext_vector_type(8)));
typedef float f32x4 __attribute__((ext_vector_type(4)));
typedef unsigned short u16x8 __attribute__((ext_vector_type(8)));
typedef unsigned short u16x4 __attribute__((ext_vector_type(4)));

__device__ __forceinline__ unsigned short f2bf(float f) {
    return __builtin_bit_cast(unsigned short, (__bf16)f);  // v_cvt RNE
}
__device__ __forceinline__ float bf2f(unsigned short u) {
    return (float)__builtin_bit_cast(__bf16, u);
}

__device__ __forceinline__ float fexp2(float x) {
#if __has_builtin(__builtin_amdgcn_exp2f)
    return __builtin_amdgcn_exp2f(x);
#else
    float r; asm("v_exp_f32 %0, %1\n\ts_nop 1" : "=v"(r) : "v"(x)); return r;
#endif
}

__device__ __forceinline__ void gload_lds16(const unsigned short* g, unsigned short* l) {
    __builtin_amdgcn_global_load_lds(
        (const __attribute__((address_space(1))) unsigned int*)g,
        (__attribute__((address_space(3))) unsigned int*)l, 16, 0, 0);
}

#define VMW(n) asm volatile("s_waitcnt vmcnt(" #n ")" ::: "memory")
#define SBAR() __builtin_amdgcn_s_barrier()
#define SCHED0() __builtin_amdgcn_sched_barrier(0)

// Q pre-scale: 1/sqrt(64) * log2(e), folded into the QKV GEMM epilogue (Q cols only)
#define QSCALE 0.18033688011112042f

// ---------------- LayerNorm: fp32 in -> bf16 out (E=1024, one row per block) ----------------
__global__ __launch_bounds__(256) void ln_kernel(
    const float* __restrict__ x, const float* __restrict__ g,
    const float* __restrict__ b, unsigned short* __restrict__ out)
{
    const int row = blockIdx.x;
    const int tid = threadIdx.x;
    const float4 v = reinterpret_cast<const float4*>(x + (size_t)row * 1024)[tid];
    float s = v.x + v.y + v.z + v.w;
    float q = v.x * v.x + v.y * v.y + v.z * v.z + v.w * v.w;
#pragma unroll
    for (int off = 32; off >= 1; off >>= 1) {
        s += __shfl_xor(s, off);
        q += __shfl_xor(q, off);
    }
    __shared__ float ss[4], sq[4];
    const int wid = tid >> 6, lane = tid & 63;
    if (lane == 0) { ss[wid] = s; sq[wid] = q; }
    __syncthreads();
    s = ss[0] + ss[1] + ss[2] + ss[3];
    q = sq[0] + sq[1] + sq[2] + sq[3];
    const float mu = s * (1.0f / 1024.0f);
    const float var = q * (1.0f / 1024.0f) - mu * mu;
    const float rs = rsqrtf(var + 1e-5f);
    const float4 gv = reinterpret_cast<const float4*>(g)[tid];
    const float4 bv = reinterpret_cast<const float4*>(b)[tid];
    u16x4 o;
    o[0] = f2bf((v.x - mu) * rs * gv.x + bv.x);
    o[1] = f2bf((v.y - mu) * rs * gv.y + bv.y);
    o[2] = f2bf((v.z - mu) * rs * gv.z + bv.z);
    o[3] = f2bf((v.w - mu) * rs * gv.w + bv.w);
    reinterpret_cast<u16x4*>(out + (size_t)row * 1024)[tid] = o;
}

// ---------------- Weight convert + transpose: W[K][N] fp32 -> Wt[N][K] bf16 ----------------
__global__ __launch_bounds__(256) void convT_kernel(
    const float* __restrict__ W, unsigned short* __restrict__ Wt, int K, int N)
{
    __shared__ float t[32][33];
    const int n0 = blockIdx.x * 32, k0 = blockIdx.y * 32;
    const int tx = threadIdx.x & 31;
    const int ty = threadIdx.x >> 5;
#pragma unroll
    for (int i = 0; i < 4; i++)
        t[ty + 8 * i][tx] = W[(size_t)(k0 + ty + 8 * i) * N + (n0 + tx)];
    __syncthreads();
#pragma unroll
    for (int i = 0; i < 4; i++)
        Wt[(size_t)(n0 + ty + 8 * i) * K + (k0 + tx)] = f2bf(t[tx][ty + 8 * i]);
}

// 4 square E x E transposes in one dispatch (z picks the matrix; dsts contiguous)
__global__ __launch_bounds__(256) void convT4_kernel(
    const float* __restrict__ A0, const float* __restrict__ A1,
    const float* __restrict__ A2, const float* __restrict__ A3,
    unsigned short* __restrict__ Wt)
{
    constexpr int E = 1024;
    const int z = blockIdx.z;
    const float* W = (z == 0) ? A0 : (z == 1) ? A1 : (z == 2) ? A2 : A3;
    unsigned short* dst = Wt + (size_t)z * E * E;
    __shared__ float t[32][33];
    const int n0 = blockIdx.x * 32, k0 = blockIdx.y * 32;
    const int tx = threadIdx.x & 31;
    const int ty = threadIdx.x >> 5;
#pragma unroll
    for (int i = 0; i < 4; i++)
        t[ty + 8 * i][tx] = W[(size_t)(k0 + ty + 8 * i) * E + (n0 + tx)];
    __syncthreads();
#pragma unroll
    for (int i = 0; i < 4; i++)
        dst[(size_t)(n0 + ty + 8 * i) * E + (k0 + tx)] = f2bf(t[tx][ty + 8 * i]);
}

// ---------------- 128x128 m97-structure GEMM (Wo): out fp32 = acc + resid ------------
__global__ __launch_bounds__(256) void gemm128_kernel(
    const unsigned short* __restrict__ A, const unsigned short* __restrict__ Bt,
    const float* __restrict__ resid, float* __restrict__ out, int M, int N, int K)
{
    __shared__ unsigned short Al[128][64];
    __shared__ unsigned short Bl[128][64];
    const int tid = threadIdx.x;
    const int lane = tid & 63, wid = tid >> 6;
    const int wr = wid >> 1, wc = wid & 1;
    const int li = lane & 15, lg = lane >> 4;
    const int m0 = blockIdx.y * 128, n0 = blockIdx.x * 128;
    const int srow = lane >> 3;
    const int schunk = ((lane & 7) ^ srow) * 8;
    const unsigned short* Asrc = A + (size_t)(m0 + wid * 32 + srow) * K + schunk;
    const unsigned short* Bsrc = Bt + (size_t)(n0 + wid * 32 + srow) * K + schunk;
    f32x4 acc[4][4] = {};

    for (int k0 = 0; k0 < K; k0 += 64) {
        __syncthreads();
#pragma unroll
        for (int i = 0; i < 4; i++) {
            gload_lds16(Asrc + k0 + (size_t)i * 8 * K, &Al[wid * 32 + i * 8][0]);
            gload_lds16(Bsrc + k0 + (size_t)i * 8 * K, &Bl[wid * 32 + i * 8][0]);
        }
        __syncthreads();
#pragma unroll
        for (int ks = 0; ks < 2; ks++) {
            bf16x8 af[4], bfr[4];
#pragma unroll
            for (int m = 0; m < 4; m++)
                af[m] = *reinterpret_cast<const bf16x8*>(
                    &Al[wr * 64 + m * 16 + li][((ks * 4 + lg) ^ (li & 7)) * 8]);
#pragma unroll
            for (int n = 0; n < 4; n++)
                bfr[n] = *reinterpret_cast<const bf16x8*>(
                    &Bl[wc * 64 + n * 16 + li][((ks * 4 + lg) ^ (li & 7)) * 8]);
#pragma unroll
            for (int m = 0; m < 4; m++)
#pragma unroll
                for (int n = 0; n < 4; n++)
                    acc[m][n] = __builtin_amdgcn_mfma_f32_16x16x32_bf16(af[m], bfr[n], acc[m][n], 0, 0, 0);
        }
    }

#pragma unroll
    for (int m = 0; m < 4; m++)
#pragma unroll
        for (int r = 0; r < 4; r++) {
            const int row = m0 + wr * 64 + m * 16 + lg * 4 + r;
#pragma unroll
            for (int n = 0; n < 4; n++) {
                const int col = n0 + wc * 64 + n * 16 + li;
                out[(size_t)row * N + col] = acc[m][n][r] + resid[(size_t)row * N + col];
            }
        }
}

// ---------------- 256x256 8-phase GEMM body (T1+T2+T3+T4+T5), stamped per-use -----------
// Separate kernel symbols + constexpr dims: rule #19 isolation (r11/r12 A/B: a sibling
// template instantiation cost W1 −43% with identical source) + constant-folded addressing.
// Schedule identical to r12 (proven 85µs/34% MfmaUtil @ W1).
// EPI 2: bf16 gelu(acc+bias); EPI 4: bf16 raw partial (split-K); EPI 5: bf16 QKV.
#define DEFINE_GEMM256(NAME, EPI, SPLITK, MM, NN, KK)                                        \
__global__ __launch_bounds__(512, 2) void NAME(                                              \
    const unsigned short* __restrict__ A, const unsigned short* __restrict__ Bt,             \
    const float* __restrict__ bias, void* __restrict__ out)                                  \
{                                                                                            \
    constexpr int M = MM, N = NN, K = KK;                                                    \
    constexpr int GRID = SPLITK * (M >> 8) * (N >> 8);                                       \
    constexpr int nblk = (M >> 8) * (N >> 8);                                                \
    constexpr int cpx = GRID >> 3;                                                           \
    constexpr int nx = N >> 8;                                                               \
    constexpr int kLen = (SPLITK == 2) ? (K >> 1) : K;                                       \
    constexpr int NI = kLen >> 7;                                                            \
    __shared__ __align__(16) unsigned short Al[2][256][64];                                  \
    __shared__ __align__(16) unsigned short Bl[2][256][64];                                  \
    const int tid = threadIdx.x;                                                             \
    const int lane = tid & 63, wid = tid >> 6;                                               \
    const int wr = wid >> 2, wc = wid & 3;                                                   \
    const int li = lane & 15, lg = lane >> 4;                                                \
    const int swz = ((int)blockIdx.x & 7) * cpx + ((int)blockIdx.x >> 3);                    \
    int tsw = swz, sid = 0;                                                                  \
    if (SPLITK == 2) { sid = (swz >= nblk) ? 1 : 0; tsw = swz - sid * nblk; }                \
    const int bx = tsw % nx, by = tsw / nx;                                                  \
    const int m0 = by * 256, n0 = bx * 256;                                                  \
    const int kOff = (SPLITK == 2) ? sid * (K >> 1) : 0;                                     \
    const int srow = lane >> 3;                                                              \
    const int sgc = ((lane & 7) ^ srow) * 8;                                                 \
    const unsigned short* aSrc = A + (size_t)(m0 + wid * 16 + srow) * K + kOff + sgc;        \
    const unsigned short* bSrc = Bt + (size_t)(n0 + wid * 16 + srow) * K + kOff + sgc;       \
    unsigned short* aDst = &Al[0][wid * 16][0];                                              \
    unsigned short* bDst = &Bl[0][wid * 16][0];                                              \
    auto stA = [&](int u, int h) {                                                           \
        const unsigned short* s = aSrc + (size_t)(h * 128) * K + u * 64;                     \
        unsigned short* d = aDst + (u & 1) * (256 * 64) + h * 128 * 64;                      \
        gload_lds16(s, d);                                                                   \
        gload_lds16(s + (size_t)8 * K, d + 8 * 64);                                          \
    };                                                                                       \
    auto stB = [&](int u, int h) {                                                           \
        const unsigned short* s = bSrc + (size_t)(h * 128) * K + u * 64;                     \
        unsigned short* d = bDst + (u & 1) * (256 * 64) + h * 128 * 64;                      \
        gload_lds16(s, d);                                                                   \
        gload_lds16(s + (size_t)8 * K, d + 8 * 64);                                          \
    };                                                                                       \
    f32x4 acc[8][4] = {};                                                                    \
    bf16x8 af[8], bn0[4], bn1[4];                                                            \
    auto ldA = [&](int buf, int mh) {                                                        \
        _Pragma("unroll")                                                                    \
        for (int m = 0; m < 4; m++)                                                          \
            _Pragma("unroll")                                                                \
            for (int ks = 0; ks < 2; ks++)                                                   \
                af[m * 2 + ks] = *reinterpret_cast<const bf16x8*>(                           \
                    &Al[buf][wr * 128 + mh * 64 + m * 16 + li][((ks * 4 + lg) ^ (li & 7)) * 8]); \
    };                                                                                       \
    auto ldB = [&](bf16x8* dst, int buf, int nh) {                                           \
        _Pragma("unroll")                                                                    \
        for (int n = 0; n < 2; n++)                                                          \
            _Pragma("unroll")                                                                \
            for (int ks = 0; ks < 2; ks++)                                                   \
                dst[n * 2 + ks] = *reinterpret_cast<const bf16x8*>(                          \
                    &Bl[buf][wc * 64 + nh * 32 + n * 16 + li][((ks * 4 + lg) ^ (li & 7)) * 8]); \
    };                                                                                       \
    auto quad = [&](const bf16x8* bfr, int mh, int nh) {                                     \
        __builtin_amdgcn_s_setprio(1);                                                       \
        _Pragma("unroll")                                                                    \
        for (int ks = 0; ks < 2; ks++)                                                       \
            _Pragma("unroll")                                                                \
            for (int m = 0; m < 4; m++)                                                      \
                _Pragma("unroll")                                                            \
                for (int n = 0; n < 2; n++)                                                  \
                    acc[mh * 4 + m][nh * 2 + n] = __builtin_amdgcn_mfma_f32_16x16x32_bf16(   \
                        af[m * 2 + ks], bfr[n * 2 + ks], acc[mh * 4 + m][nh * 2 + n], 0, 0, 0); \
        __builtin_amdgcn_s_setprio(0);                                                       \
    };                                                                                       \
    stA(0, 0); stA(0, 1); stB(0, 0); stB(0, 1);                                              \
    stB(1, 0); stB(1, 1);                                                                    \
    VMW(4);                                                                                  \
    SBAR(); SCHED0();                                                                        \
    for (int I = 0; I < NI; ++I) {                                                           \
        const int u0 = 2 * I;                                                                \
        const bool hn = (I + 1 < NI);                                                        \
        ldA(0, 0); ldB(bn0, 0, 0);                                                           \
        stA(u0 + 1, 0);                                                                      \
        SBAR(); SCHED0();                                                                    \
        quad(bn0, 0, 0);                                                                     \
        SBAR(); SCHED0();                                                                    \
        ldB(bn1, 0, 1);                                                                      \
        stA(u0 + 1, 1);                                                                      \
        SBAR(); SCHED0();                                                                    \
        quad(bn1, 0, 1);                                                                     \
        SBAR(); SCHED0();                                                                    \
        ldA(0, 1);                                                                           \
        if (hn) stB(u0 + 2, 0);                                                              \
        SBAR(); SCHED0();                                                                    \
        quad(bn1, 1, 1);                                                                     \
        SBAR(); SCHED0();                                                                    \
        if (hn) stB(u0 + 2, 1);                                                              \
        SBAR(); SCHED0();                                                                    \
        quad(bn0, 1, 0);                                                                     \
        if (hn) { VMW(4); } else { VMW(0); }                                                 \
        SBAR(); SCHED0();                                                                    \
        ldA(1, 0); ldB(bn0, 1, 0);                                                           \
        if (hn) stA(u0 + 2, 0);                                                              \
        SBAR(); SCHED0();                                                                    \
        quad(bn0, 0, 0);                                                                     \
        SBAR(); SCHED0();                                                                    \
        ldB(bn1, 1, 1);                                                                      \
        if (hn) stA(u0 + 2, 1);                                                              \
        SBAR(); SCHED0();                                                                    \
        quad(bn1, 0, 1);                                                                     \
        SBAR(); SCHED0();                                                                    \
        ldA(1, 1);                                                                           \
        if (hn) stB(u0 + 3, 0);                                                              \
        SBAR(); SCHED0();                                                                    \
        quad(bn1, 1, 1);                                                                     \
        SBAR(); SCHED0();                                                                    \
        if (hn) stB(u0 + 3, 1);                                                              \
        SBAR(); SCHED0();                                                                    \
        quad(bn0, 1, 0);                                                                     \
        if (hn) { VMW(4); } else { VMW(0); }                                                 \
        SBAR(); SCHED0();                                                                    \
    }                                                                                        \
    _Pragma("unroll")                                                                        \
    for (int ma = 0; ma < 8; ma++) {                                                         \
        _Pragma("unroll")                                                                    \
        for (int r = 0; r < 4; r++) {                                                        \
            const int row = m0 + wr * 128 + ma * 16 + lg * 4 + r;                            \
            _Pragma("unroll")                                                                \
            for (int n = 0; n < 4; n++) {                                                    \
                const int col = n0 + wc * 64 + n * 16 + li;                                  \
                float v = acc[ma][n][r];                                                     \
                if constexpr (EPI == 2) {                                                    \
                    v += bias[col];                                                          \
                    float a2 = 1.5957691216f * (v + 0.044715f * v * v * v);                  \
                    a2 = fminf(a2, 80.0f);                                                   \
                    const float t = __expf(a2);                                              \
                    v = v * t * __builtin_amdgcn_rcpf(t + 1.0f);                             \
                    reinterpret_cast<unsigned short*>(out)[(size_t)row * N + col] = f2bf(v); \
                } else if constexpr (EPI == 4) {                                             \
                    unsigned short* op = reinterpret_cast<unsigned short*>(out) + (size_t)sid * M * N; \
                    op[(size_t)row * N + col] = f2bf(v);                                     \
                } else {                                                                     \
                    const float sc = (col < 1024) ? QSCALE : 1.0f;                           \
                    reinterpret_cast<unsigned short*>(out)[(size_t)row * N + col] = f2bf(v * sc); \
                }                                                                            \
            }                                                                                \
        }                                                                                    \
    }                                                                                        \
}

DEFINE_GEMM256(gemm_qkv, 5, 1, 8192, 3072, 1024)   // grid 384
DEFINE_GEMM256(gemm_w1,  2, 1, 8192, 4096, 1024)   // grid 512
DEFINE_GEMM256(gemm_w2,  4, 2, 8192, 1024, 4096)   // grid 256 (split-K=2)

// ---------------- W2 split-K reduce: d_out = p0 + p1 + b2 + x1  (bf16 partials) --------------
__global__ __launch_bounds__(256) void w2red_kernel(
    const unsigned short* __restrict__ p0, const unsigned short* __restrict__ p1,
    const float* __restrict__ x1, const float* __restrict__ b2,
    float* __restrict__ out)
{
    const int i = blockIdx.x * 256 + threadIdx.x;     // 8-element index
    const u16x8 a = reinterpret_cast<const u16x8*>(p0)[i];
    const u16x8 b = reinterpret_cast<const u16x8*>(p1)[i];
    const float4 r0 = reinterpret_cast<const float4*>(x1)[2 * i];
    const float4 r1 = reinterpret_cast<const float4*>(x1)[2 * i + 1];
    const int cb = (i & 127) * 8;                     // col base within E=1024
    const float4 bb0 = *reinterpret_cast<const float4*>(b2 + cb);
    const float4 bb1 = *reinterpret_cast<const float4*>(b2 + cb + 4);
    float4 o0, o1;
    o0.x = bf2f(a[0]) + bf2f(b[0]) + r0.x + bb0.x;
    o0.y = bf2f(a[1]) + bf2f(b[1]) + r0.y + bb0.y;
    o0.z = bf2f(a[2]) + bf2f(b[2]) + r0.z + bb0.z;
    o0.w = bf2f(a[3]) + bf2f(b[3]) + r0.w + bb0.w;
    o1.x = bf2f(a[4]) + bf2f(b[4]) + r1.x + bb1.x;
    o1.y = bf2f(a[5]) + bf2f(b[5]) + r1.y + bb1.y;
    o1.z = bf2f(a[6]) + bf2f(b[6]) + r1.z + bb1.z;
    o1.w = bf2f(a[7]) + bf2f(b[7]) + r1.w + bb1.w;
    reinterpret_cast<float4*>(out)[2 * i] = o0;
    reinterpret_cast<float4*>(out)[2 * i + 1] = o1;
}

// ---------------- Flash attention (causal), QBLK=128, 8 waves, no-max exp2 softmax ----------
// QKV [8192][3072] (Q pre-scaled). grid 512 = 8 balanced pairs (qt, 15-qt) x 64 bh.
// LDS 48KB -> 3 blocks/CU (24 waves/CU). Pl rotation by row&7: write AND read conflict-free
// within 8-lane groups (r13 analysis: old 2*(q>>2) rotation was 4-way on pa reads).
__global__ __launch_bounds__(512, 6) void flash_kernel(
    const unsigned short* __restrict__ QKV, unsigned short* __restrict__ O)
{
    constexpr int C = 2048, HD3 = 3072, HD = 1024;
    __shared__ unsigned short Kl[2][64][64];  // [key][d], chunk XOR (row&7) via source swizzle
    __shared__ unsigned short Vt[2][64][64];  // [d][key], chunk = (key>>3)^(d&7)^(d>>3)
    __shared__ unsigned short Pl[128][64];    // [q][key], chunk = (key>>3 + q)&7, elem key&7
    const int tid = threadIdx.x;
    const int lane = tid & 63, wid = tid >> 6;   // 8 waves
    const int li = lane & 15, lg = lane >> 4;
    const int flat = blockIdx.x;
    const int bh = flat & 63;                    // one head's blocks share an XCD
    const int pair = flat >> 6;                  // 0..7
    const int b = bh >> 4, h = bh & 15;
    const size_t baseQ = ((size_t)b * C) * HD3 + (size_t)h * 64;
    const size_t baseK = baseQ + 1024;
    const size_t baseV = baseQ + 2048;
    const size_t baseO = ((size_t)b * C) * HD + (size_t)h * 64;

    const int srow = lane >> 3;                  // 0..7
    const int sgc = ((lane & 7) ^ srow) * 8;     // K pre-swizzled global chunk
    const int vx = lane & 7;                     // V: d-block [vx*8, vx*8+8)

    const u16x8 onesu = {0x3F80, 0x3F80, 0x3F80, 0x3F80, 0x3F80, 0x3F80, 0x3F80, 0x3F80};
    const bf16x8 ones = __builtin_bit_cast(bf16x8, onesu);

    for (int half = 0; half < 2; half++) {
        const int qt = (half == 0) ? pair : (15 - pair);
        const int q0 = qt * 128;
        const int qrow = q0 + wid * 16 + li;
        const bf16x8 qa0 = *reinterpret_cast<const bf16x8*>(&QKV[baseQ + (size_t)qrow * HD3 + lg * 8]);
        const bf16x8 qa1 = *reinterpret_cast<const bf16x8*>(&QKV[baseQ + (size_t)qrow * HD3 + 32 + lg * 8]);
        const int myrow0 = q0 + wid * 16 + lg * 4;

        f32x4 acc[4] = {};
        f32x4 accl = {};
        int cur = 0;
        const int nt = 2 * qt + 2;               // KV tiles of 64 keys

        // stage one KV tile: wave wid handles keys [wid*8, wid*8+8)
        auto stage = [&](int k0s, int buf) {
            gload_lds16(&QKV[baseK + (size_t)(k0s + wid * 8 + srow) * HD3 + sgc],
                        &Kl[buf][wid * 8][0]);
            const u16x8 vv = *reinterpret_cast<const u16x8*>(
                &QKV[baseV + (size_t)(k0s + wid * 8 + srow) * HD3 + vx * 8]);
#pragma unroll
            for (int j = 0; j < 8; j++)
                Vt[buf][vx * 8 + j][((wid ^ j ^ vx) & 7) * 8 + srow] = vv[j];
        };

        __syncthreads();
        stage(0, 0);
        __syncthreads();

        auto tile_body = [&](int t, bool diag, bool pre) {
            const int k0 = t * 64;
            u16x8 vr;
            if (pre) {  // issue next-tile loads early (hide under compute)
                const int kn = k0 + 64;
                gload_lds16(&QKV[baseK + (size_t)(kn + wid * 8 + srow) * HD3 + sgc],
                            &Kl[cur ^ 1][wid * 8][0]);
                vr = *reinterpret_cast<const u16x8*>(
                    &QKV[baseV + (size_t)(kn + wid * 8 + srow) * HD3 + vx * 8]);
            }

            // S = Q K^T (Q pre-scaled; S in log2 domain)
            f32x4 s[4] = {};
            __builtin_amdgcn_s_setprio(1);
#pragma unroll
            for (int n = 0; n < 4; n++) {
                const int row = n * 16 + li;
                const bf16x8 kb0 = *reinterpret_cast<const bf16x8*>(
                    &Kl[cur][row][(lg ^ (li & 7)) * 8]);
                const bf16x8 kb1 = *reinterpret_cast<const bf16x8*>(
                    &Kl[cur][row][((4 + lg) ^ (li & 7)) * 8]);
                s[n] = __builtin_amdgcn_mfma_f32_16x16x32_bf16(qa0, kb0, s[n], 0, 0, 0);
                s[n] = __builtin_amdgcn_mfma_f32_16x16x32_bf16(qa1, kb1, s[n], 0, 0, 0);
            }
            __builtin_amdgcn_s_setprio(0);

            // P = exp2(S), causal zeroing on diag tiles; rotation by row&7 (conflict-free)
#pragma unroll
            for (int n = 0; n < 4; n++) {
#pragma unroll
                for (int r = 0; r < 4; r++) {
                    float pv = fexp2(s[n][r]);
                    if (diag) {
                        const int key = k0 + n * 16 + li;
                        if (key > myrow0 + r) pv = 0.0f;
                    }
                    Pl[wid * 16 + lg * 4 + r]
                      [((2 * n + (li >> 3) + lg * 4 + r) & 7) * 8 + (li & 7)] = f2bf(pv);
                }
            }

            if (pre) {  // V regs arrived; fill Vt[next]
#pragma unroll
                for (int j = 0; j < 8; j++)
                    Vt[cur ^ 1][vx * 8 + j][((wid ^ j ^ vx) & 7) * 8 + srow] = vr[j];
            }

            // O += P V ; row-sums via ones-MFMA
            __builtin_amdgcn_s_setprio(1);
#pragma unroll
            for (int ks = 0; ks < 2; ks++) {
                const bf16x8 pa = *reinterpret_cast<const bf16x8*>(
                    &Pl[wid * 16 + li][((ks * 4 + lg + li) & 7) * 8]);
#pragma unroll
                for (int n = 0; n < 4; n++) {
                    const int row = n * 16 + li;
                    const bf16x8 vb = *reinterpret_cast<const bf16x8*>(
                        &Vt[cur][row][(((ks * 4 + lg) ^ (row & 7) ^ (row >> 3)) & 7) * 8]);
                    acc[n] = __builtin_amdgcn_mfma_f32_16x16x32_bf16(pa, vb, acc[n], 0, 0, 0);
                }
                accl = __builtin_amdgcn_mfma_f32_16x16x32_bf16(pa, ones, accl, 0, 0, 0);
            }
            __builtin_amdgcn_s_setprio(0);

            __syncthreads();
            cur ^= 1;
        };

        for (int t = 0; t < nt; t++) tile_body(t, t >= nt - 2, t < nt - 1);

        // epilogue: O = acc / l
#pragma unroll
        for (int r = 0; r < 4; r++) {
            const float inv = 1.0f / accl[r];
            const int row = myrow0 + r;
#pragma unroll
            for (int n = 0; n < 4; n++)
                O[baseO + (size_t)row * HD + n * 16 + li] = f2bf(acc[n][r] * inv);
        }
    }
}

// ---------------- launch ----------------
extern "C" void kernel_launch(void* const* d_in, const int* in_sizes, int n_in,
                              void* d_out, int out_size, void* d_ws, size_t ws_size,
                              hipStream_t stream) {
    constexpr int B = 4, C = 2048, E = 1024, H = 16, FF = 4096;
    constexpr int M = B * C;  // 8192

    const float* x     = (const float*)d_in[0];
    const float* ln1_g = (const float*)d_in[1];
    const float* ln1_b = (const float*)d_in[2];
    const float* Wq    = (const float*)d_in[3];
    const float* Wk    = (const float*)d_in[4];
    const float* Wv    = (const float*)d_in[5];
    const float* Wo    = (const float*)d_in[6];
    const float* ln2_g = (const float*)d_in[7];
    const float* ln2_b = (const float*)d_in[8];
    const float* W1    = (const float*)d_in[9];
    const float* b1    = (const float*)d_in[10];
    const float* W2    = (const float*)d_in[11];
    const float* b2    = (const float*)d_in[12];

    char* p = (char*)d_ws;
    auto alloc = [&](size_t bytes) { void* r = (void*)p; p += (bytes + 255) & ~(size_t)255; return r; };
    unsigned short* WqT  = (unsigned short*)alloc((size_t)E * E * 2);   // Wq/Wk/Wv/Wo contiguous
    unsigned short* WkT  = (unsigned short*)alloc((size_t)E * E * 2);
    unsigned short* WvT  = (unsigned short*)alloc((size_t)E * E * 2);
    unsigned short* WoT  = (unsigned short*)alloc((size_t)E * E * 2);
    unsigned short* W1T  = (unsigned short*)alloc((size_t)E * FF * 2);
    unsigned short* W2T  = (unsigned short*)alloc((size_t)FF * E * 2);
    unsigned short* hb   = (unsigned short*)alloc((size_t)M * E * 2);   // reused as W2 partials
    unsigned short* QKVb = (unsigned short*)alloc((size_t)M * 3 * E * 2);
    unsigned short* attn = (unsigned short*)alloc((size_t)M * E * 2);
    float*          x1   = (float*)alloc((size_t)M * E * 4);
    unsigned short* h2   = (unsigned short*)alloc((size_t)M * E * 2);
    unsigned short* ff   = (unsigned short*)alloc((size_t)M * FF * 2);
    (void)WkT; (void)WvT;
    unsigned short* parts = hb;  // 2 x 16MB bf16 partials: spans hb+QKVb (both dead by then)

    // weight conversion / transpose
    convT4_kernel<<<dim3(E / 32, E / 32, 4), 256, 0, stream>>>(Wq, Wk, Wv, Wo, WqT);
    convT_kernel<<<dim3(FF / 32, E / 32), 256, 0, stream>>>(W1, W1T, E, FF);
    convT_kernel<<<dim3(E / 32, FF / 32), 256, 0, stream>>>(W2, W2T, FF, E);

    // LN1
    ln_kernel<<<M, 256, 0, stream>>>(x, ln1_g, ln1_b, hb);

    // fused QKV projection (N=3072), Q columns pre-scaled; 8-phase 256^2, grid 384
    gemm_qkv<<<dim3(384), 512, 0, stream>>>(hb, WqT, nullptr, QKVb);

    // attention (QBLK=128, 8 waves, 512 blocks)
    flash_kernel<<<dim3(512), 512, 0, stream>>>(QKVb, attn);

    // output projection + residual (m97 128^2, grid 512 = 2/CU)
    gemm128_kernel<<<dim3(E / 128, M / 128), 256, 0, stream>>>(
        attn, WoT, x, x1, M, E, E);

    // LN2
    ln_kernel<<<M, 256, 0, stream>>>(x1, ln2_g, ln2_b, h2);

    // FFN up + GELU (8-phase 256^2, grid 512)
    gemm_w1<<<dim3(512), 512, 0, stream>>>(h2, W1T, b1, ff);

    // FFN down: split-K=2 (grid 256 = full machine), bf16 partials, then reduce
    gemm_w2<<<dim3(256), 512, 0, stream>>>(ff, W2T, nullptr, parts);
    w2red_kernel<<<dim3(M * E / 8 / 256), 256, 0, stream>>>(
        parts, parts + (size_t)M * E, x1, b2, (float*)d_out);
}

// Round 15
// 393.169 us; speedup vs baseline: 1.1339x; 1.1339x over previous
//
#include <hip/hip_runtime.h>

typedef __bf16 bf16x8 __attribute__((ext_vector_type(8)));
typedef float f32x4 __attribute__((ext_vector_type(4)));
typedef unsigned short u16x8 __attribute__((ext_vector_type(8)));
typedef unsigned short u16x4 __attribute__((ext_vector_type(4)));

__device__ __forceinline__ unsigned short f2bf(float f) {
    return __builtin_bit_cast(unsigned short, (__bf16)f);  // v_cvt RNE
}
__device__ __forceinline__ float bf2f(unsigned short u) {
    return (float)__builtin_bit_cast(__bf16, u);
}

__device__ __forceinline__ float fexp2(float x) {
#if __has_builtin(__builtin_amdgcn_exp2f)
    return __builtin_amdgcn_exp2f(x);
#else
    float r; asm("v_exp_f32 %0, %1\n\ts_nop 1" : "=v"(r) : "v"(x)); return r;
#endif
}

__device__ __forceinline__ void gload_lds16(const unsigned short* g, unsigned short* l) {
    __builtin_amdgcn_global_load_lds(
        (const __attribute__((address_space(1))) unsigned int*)g,
        (__attribute__((address_space(3))) unsigned int*)l, 16, 0, 0);
}

#define VMW(n) asm volatile("s_waitcnt vmcnt(" #n ")" ::: "memory")
#define SBAR() __builtin_amdgcn_s_barrier()
#define SCHED0() __builtin_amdgcn_sched_barrier(0)

// Q pre-scale: 1/sqrt(64) * log2(e), folded into the QKV GEMM epilogue (Q cols only)
#define QSCALE 0.18033688011112042f

// ---------------- LayerNorm: fp32 in -> bf16 out (E=1024, one row per block) ----------------
__global__ __launch_bounds__(256) void ln_kernel(
    const float* __restrict__ x, const float* __restrict__ g,
    const float* __restrict__ b, unsigned short* __restrict__ out)
{
    const int row = blockIdx.x;
    const int tid = threadIdx.x;
    const float4 v = reinterpret_cast<const float4*>(x + (size_t)row * 1024)[tid];
    float s = v.x + v.y + v.z + v.w;
    float q = v.x * v.x + v.y * v.y + v.z * v.z + v.w * v.w;
#pragma unroll
    for (int off = 32; off >= 1; off >>= 1) {
        s += __shfl_xor(s, off);
        q += __shfl_xor(q, off);
    }
    __shared__ float ss[4], sq[4];
    const int wid = tid >> 6, lane = tid & 63;
    if (lane == 0) { ss[wid] = s; sq[wid] = q; }
    __syncthreads();
    s = ss[0] + ss[1] + ss[2] + ss[3];
    q = sq[0] + sq[1] + sq[2] + sq[3];
    const float mu = s * (1.0f / 1024.0f);
    const float var = q * (1.0f / 1024.0f) - mu * mu;
    const float rs = rsqrtf(var + 1e-5f);
    const float4 gv = reinterpret_cast<const float4*>(g)[tid];
    const float4 bv = reinterpret_cast<const float4*>(b)[tid];
    u16x4 o;
    o[0] = f2bf((v.x - mu) * rs * gv.x + bv.x);
    o[1] = f2bf((v.y - mu) * rs * gv.y + bv.y);
    o[2] = f2bf((v.z - mu) * rs * gv.z + bv.z);
    o[3] = f2bf((v.w - mu) * rs * gv.w + bv.w);
    reinterpret_cast<u16x4*>(out + (size_t)row * 1024)[tid] = o;
}

// ---------------- Weight convert + transpose: W[K][N] fp32 -> Wt[N][K] bf16 ----------------
__global__ __launch_bounds__(256) void convT_kernel(
    const float* __restrict__ W, unsigned short* __restrict__ Wt, int K, int N)
{
    __shared__ float t[32][33];
    const int n0 = blockIdx.x * 32, k0 = blockIdx.y * 32;
    const int tx = threadIdx.x & 31;
    const int ty = threadIdx.x >> 5;
#pragma unroll
    for (int i = 0; i < 4; i++)
        t[ty + 8 * i][tx] = W[(size_t)(k0 + ty + 8 * i) * N + (n0 + tx)];
    __syncthreads();
#pragma unroll
    for (int i = 0; i < 4; i++)
        Wt[(size_t)(n0 + ty + 8 * i) * K + (k0 + tx)] = f2bf(t[tx][ty + 8 * i]);
}

// 4 square E x E transposes in one dispatch (z picks the matrix; dsts contiguous)
__global__ __launch_bounds__(256) void convT4_kernel(
    const float* __restrict__ A0, const float* __restrict__ A1,
    const float* __restrict__ A2, const float* __restrict__ A3,
    unsigned short* __restrict__ Wt)
{
    constexpr int E = 1024;
    const int z = blockIdx.z;
    const float* W = (z == 0) ? A0 : (z == 1) ? A1 : (z == 2) ? A2 : A3;
    unsigned short* dst = Wt + (size_t)z * E * E;
    __shared__ float t[32][33];
    const int n0 = blockIdx.x * 32, k0 = blockIdx.y * 32;
    const int tx = threadIdx.x & 31;
    const int ty = threadIdx.x >> 5;
#pragma unroll
    for (int i = 0; i < 4; i++)
        t[ty + 8 * i][tx] = W[(size_t)(k0 + ty + 8 * i) * E + (n0 + tx)];
    __syncthreads();
#pragma unroll
    for (int i = 0; i < 4; i++)
        dst[(size_t)(n0 + ty + 8 * i) * E + (k0 + tx)] = f2bf(t[tx][ty + 8 * i]);
}

// ---------- 128x128 m97-structure GEMM (Wo): x1 = acc + x ; d_out = x1 + b2 (W2 base) -------
__global__ __launch_bounds__(256) void gemm128_kernel(
    const unsigned short* __restrict__ A, const unsigned short* __restrict__ Bt,
    const float* __restrict__ resid, const float* __restrict__ b2,
    float* __restrict__ out, float* __restrict__ dinit, int M, int N, int K)
{
    __shared__ unsigned short Al[128][64];
    __shared__ unsigned short Bl[128][64];
    const int tid = threadIdx.x;
    const int lane = tid & 63, wid = tid >> 6;
    const int wr = wid >> 1, wc = wid & 1;
    const int li = lane & 15, lg = lane >> 4;
    const int m0 = blockIdx.y * 128, n0 = blockIdx.x * 128;
    const int srow = lane >> 3;
    const int schunk = ((lane & 7) ^ srow) * 8;
    const unsigned short* Asrc = A + (size_t)(m0 + wid * 32 + srow) * K + schunk;
    const unsigned short* Bsrc = Bt + (size_t)(n0 + wid * 32 + srow) * K + schunk;
    f32x4 acc[4][4] = {};

    for (int k0 = 0; k0 < K; k0 += 64) {
        __syncthreads();
#pragma unroll
        for (int i = 0; i < 4; i++) {
            gload_lds16(Asrc + k0 + (size_t)i * 8 * K, &Al[wid * 32 + i * 8][0]);
            gload_lds16(Bsrc + k0 + (size_t)i * 8 * K, &Bl[wid * 32 + i * 8][0]);
        }
        __syncthreads();
#pragma unroll
        for (int ks = 0; ks < 2; ks++) {
            bf16x8 af[4], bfr[4];
#pragma unroll
            for (int m = 0; m < 4; m++)
                af[m] = *reinterpret_cast<const bf16x8*>(
                    &Al[wr * 64 + m * 16 + li][((ks * 4 + lg) ^ (li & 7)) * 8]);
#pragma unroll
            for (int n = 0; n < 4; n++)
                bfr[n] = *reinterpret_cast<const bf16x8*>(
                    &Bl[wc * 64 + n * 16 + li][((ks * 4 + lg) ^ (li & 7)) * 8]);
#pragma unroll
            for (int m = 0; m < 4; m++)
#pragma unroll
                for (int n = 0; n < 4; n++)
                    acc[m][n] = __builtin_amdgcn_mfma_f32_16x16x32_bf16(af[m], bfr[n], acc[m][n], 0, 0, 0);
        }
    }

#pragma unroll
    for (int m = 0; m < 4; m++)
#pragma unroll
        for (int r = 0; r < 4; r++) {
            const int row = m0 + wr * 64 + m * 16 + lg * 4 + r;
#pragma unroll
            for (int n = 0; n < 4; n++) {
                const int col = n0 + wc * 64 + n * 16 + li;
                const float xv = acc[m][n][r] + resid[(size_t)row * N + col];
                out[(size_t)row * N + col] = xv;
                dinit[(size_t)row * N + col] = xv + b2[col];
            }
        }
}

// ---------------- 256x256 8-phase GEMM body (T1+T2+T3+T4+T5), stamped per-use -----------
// Separate kernel symbols + constexpr dims (rule #19 isolation, proven r13: W1 85µs/34%).
// EPI 2: bf16 gelu(acc+bias); EPI 5: bf16 QKV (Q cols pre-scaled); EPI 6: fp32 atomicAdd.
#define DEFINE_GEMM256(NAME, EPI, SPLITK, MM, NN, KK)                                        \
__global__ __launch_bounds__(512, 2) void NAME(                                              \
    const unsigned short* __restrict__ A, const unsigned short* __restrict__ Bt,             \
    const float* __restrict__ bias, void* __restrict__ out)                                  \
{                                                                                            \
    constexpr int M = MM, N = NN, K = KK;                                                    \
    constexpr int GRID = SPLITK * (M >> 8) * (N >> 8);                                       \
    constexpr int nblk = (M >> 8) * (N >> 8);                                                \
    constexpr int cpx = GRID >> 3;                                                           \
    constexpr int nx = N >> 8;                                                               \
    constexpr int kLen = (SPLITK == 2) ? (K >> 1) : K;                                       \
    constexpr int NI = kLen >> 7;                                                            \
    __shared__ __align__(16) unsigned short Al[2][256][64];                                  \
    __shared__ __align__(16) unsigned short Bl[2][256][64];                                  \
    const int tid = threadIdx.x;                                                             \
    const int lane = tid & 63, wid = tid >> 6;                                               \
    const int wr = wid >> 2, wc = wid & 3;                                                   \
    const int li = lane & 15, lg = lane >> 4;                                                \
    const int swz = ((int)blockIdx.x & 7) * cpx + ((int)blockIdx.x >> 3);                    \
    int tsw = swz, sid = 0;                                                                  \
    if (SPLITK == 2) { sid = (swz >= nblk) ? 1 : 0; tsw = swz - sid * nblk; }                \
    const int bx = tsw % nx, by = tsw / nx;                                                  \
    const int m0 = by * 256, n0 = bx * 256;                                                  \
    const int kOff = (SPLITK == 2) ? sid * (K >> 1) : 0;                                     \
    const int srow = lane >> 3;                                                              \
    const int sgc = ((lane & 7) ^ srow) * 8;                                                 \
    const unsigned short* aSrc = A + (size_t)(m0 + wid * 16 + srow) * K + kOff + sgc;        \
    const unsigned short* bSrc = Bt + (size_t)(n0 + wid * 16 + srow) * K + kOff + sgc;       \
    unsigned short* aDst = &Al[0][wid * 16][0];                                              \
    unsigned short* bDst = &Bl[0][wid * 16][0];                                              \
    auto stA = [&](int u, int h) {                                                           \
        const unsigned short* s = aSrc + (size_t)(h * 128) * K + u * 64;                     \
        unsigned short* d = aDst + (u & 1) * (256 * 64) + h * 128 * 64;                      \
        gload_lds16(s, d);                                                                   \
        gload_lds16(s + (size_t)8 * K, d + 8 * 64);                                          \
    };                                                                                       \
    auto stB = [&](int u, int h) {                                                           \
        const unsigned short* s = bSrc + (size_t)(h * 128) * K + u * 64;                     \
        unsigned short* d = bDst + (u & 1) * (256 * 64) + h * 128 * 64;                      \
        gload_lds16(s, d);                                                                   \
        gload_lds16(s + (size_t)8 * K, d + 8 * 64);                                          \
    };                                                                                       \
    f32x4 acc[8][4] = {};                                                                    \
    bf16x8 af[8], bn0[4], bn1[4];                                                            \
    auto ldA = [&](int buf, int mh) {                                                        \
        _Pragma("unroll")                                                                    \
        for (int m = 0; m < 4; m++)                                                          \
            _Pragma("unroll")                                                                \
            for (int ks = 0; ks < 2; ks++)                                                   \
                af[m * 2 + ks] = *reinterpret_cast<const bf16x8*>(                           \
                    &Al[buf][wr * 128 + mh * 64 + m * 16 + li][((ks * 4 + lg) ^ (li & 7)) * 8]); \
    };                                                                                       \
    auto ldB = [&](bf16x8* dst, int buf, int nh) {                                           \
        _Pragma("unroll")                                                                    \
        for (int n = 0; n < 2; n++)                                                          \
            _Pragma("unroll")                                                                \
            for (int ks = 0; ks < 2; ks++)                                                   \
                dst[n * 2 + ks] = *reinterpret_cast<const bf16x8*>(                          \
                    &Bl[buf][wc * 64 + nh * 32 + n * 16 + li][((ks * 4 + lg) ^ (li & 7)) * 8]); \
    };                                                                                       \
    auto quad = [&](const bf16x8* bfr, int mh, int nh) {                                     \
        __builtin_amdgcn_s_setprio(1);                                                       \
        _Pragma("unroll")                                                                    \
        for (int ks = 0; ks < 2; ks++)                                                       \
            _Pragma("unroll")                                                                \
            for (int m = 0; m < 4; m++)                                                      \
                _Pragma("unroll")                                                            \
                for (int n = 0; n < 2; n++)                                                  \
                    acc[mh * 4 + m][nh * 2 + n] = __builtin_amdgcn_mfma_f32_16x16x32_bf16(   \
                        af[m * 2 + ks], bfr[n * 2 + ks], acc[mh * 4 + m][nh * 2 + n], 0, 0, 0); \
        __builtin_amdgcn_s_setprio(0);                                                       \
    };                                                                                       \
    stA(0, 0); stA(0, 1); stB(0, 0); stB(0, 1);                                              \
    stB(1, 0); stB(1, 1);                                                                    \
    VMW(4);                                                                                  \
    SBAR(); SCHED0();                                                                        \
    for (int I = 0; I < NI; ++I) {                                                           \
        const int u0 = 2 * I;                                                                \
        const bool hn = (I + 1 < NI);                                                        \
        ldA(0, 0); ldB(bn0, 0, 0);                                                           \
        stA(u0 + 1, 0);                                                                      \
        SBAR(); SCHED0();                                                                    \
        quad(bn0, 0, 0);                                                                     \
        SBAR(); SCHED0();                                                                    \
        ldB(bn1, 0, 1);                                                                      \
        stA(u0 + 1, 1);                                                                      \
        SBAR(); SCHED0();                                                                    \
        quad(bn1, 0, 1);                                                                     \
        SBAR(); SCHED0();                                                                    \
        ldA(0, 1);                                                                           \
        if (hn) stB(u0 + 2, 0);                                                              \
        SBAR(); SCHED0();                                                                    \
        quad(bn1, 1, 1);                                                                     \
        SBAR(); SCHED0();                                                                    \
        if (hn) stB(u0 + 2, 1);                                                              \
        SBAR(); SCHED0();                                                                    \
        quad(bn0, 1, 0);                                                                     \
        if (hn) { VMW(4); } else { VMW(0); }                                                 \
        SBAR(); SCHED0();                                                                    \
        ldA(1, 0); ldB(bn0, 1, 0);                                                           \
        if (hn) stA(u0 + 2, 0);                                                              \
        SBAR(); SCHED0();                                                                    \
        quad(bn0, 0, 0);                                                                     \
        SBAR(); SCHED0();                                                                    \
        ldB(bn1, 1, 1);                                                                      \
        if (hn) stA(u0 + 2, 1);                                                              \
        SBAR(); SCHED0();                                                                    \
        quad(bn1, 0, 1);                                                                     \
        SBAR(); SCHED0();                                                                    \
        ldA(1, 1);                                                                           \
        if (hn) stB(u0 + 3, 0);                                                              \
        SBAR(); SCHED0();                                                                    \
        quad(bn1, 1, 1);                                                                     \
        SBAR(); SCHED0();                                                                    \
        if (hn) stB(u0 + 3, 1);                                                              \
        SBAR(); SCHED0();                                                                    \
        quad(bn0, 1, 0);                                                                     \
        if (hn) { VMW(4); } else { VMW(0); }                                                 \
        SBAR(); SCHED0();                                                                    \
    }                                                                                        \
    _Pragma("unroll")                                                                        \
    for (int ma = 0; ma < 8; ma++) {                                                         \
        _Pragma("unroll")                                                                    \
        for (int r = 0; r < 4; r++) {                                                        \
            const int row = m0 + wr * 128 + ma * 16 + lg * 4 + r;                            \
            _Pragma("unroll")                                                                \
            for (int n = 0; n < 4; n++) {                                                    \
                const int col = n0 + wc * 64 + n * 16 + li;                                  \
                float v = acc[ma][n][r];                                                     \
                if constexpr (EPI == 2) {                                                    \
                    v += bias[col];                                                          \
                    float a2 = 1.5957691216f * (v + 0.044715f * v * v * v);                  \
                    a2 = fminf(a2, 80.0f);                                                   \
                    const float t = __expf(a2);                                              \
                    v = v * t * __builtin_amdgcn_rcpf(t + 1.0f);                             \
                    reinterpret_cast<unsigned short*>(out)[(size_t)row * N + col] = f2bf(v); \
                } else if constexpr (EPI == 6) {                                             \
                    atomicAdd(reinterpret_cast<float*>(out) + (size_t)row * N + col, v);     \
                } else {                                                                     \
                    const float sc = (col < 1024) ? QSCALE : 1.0f;                           \
                    reinterpret_cast<unsigned short*>(out)[(size_t)row * N + col] = f2bf(v * sc); \
                }                                                                            \
            }                                                                                \
        }                                                                                    \
    }                                                                                        \
}

DEFINE_GEMM256(gemm_qkv, 5, 1, 8192, 3072, 1024)   // grid 384
DEFINE_GEMM256(gemm_w1,  2, 1, 8192, 4096, 1024)   // grid 512
DEFINE_GEMM256(gemm_w2a, 6, 2, 8192, 1024, 4096)   // grid 256, split-K=2, atomic into d_out

// ---------------- Flash attention (causal), r13 proven version (85µs) ----------------
// QKV [8192][3072] (Q pre-scaled by QSCALE). grid 1024 = 4 blocks/CU exactly resident.
__global__ __launch_bounds__(256, 4) void flash_kernel(
    const unsigned short* __restrict__ QKV, unsigned short* __restrict__ O)
{
    constexpr int C = 2048, HD3 = 3072, HD = 1024, NT = 32;
    __shared__ unsigned short Kl[2][64][64];  // [key][d], chunk XOR (row&7)
    __shared__ unsigned short Vt[2][64][64];  // [d][key], chunk XOR
    __shared__ unsigned short Pl[64][64];     // [q][key], chunk rotation
    const int tid = threadIdx.x;
    const int lane = tid & 63, wid = tid >> 6;
    const int li = lane & 15, lg = lane >> 4;
    const int flat = blockIdx.x;
    const int bh = flat & 63;
    const int pair = flat >> 6;
    const int b = bh >> 4, h = bh & 15;
    const size_t baseQ = ((size_t)b * C) * HD3 + (size_t)h * 64;
    const size_t baseK = baseQ + 1024;
    const size_t baseV = baseQ + 2048;
    const size_t baseO = ((size_t)b * C) * HD + (size_t)h * 64;

    const int srow = lane >> 3;
    const int sgc = ((lane & 7) ^ srow) * 8;
    const int vx = lane & 7;

    const u16x8 onesu = {0x3F80, 0x3F80, 0x3F80, 0x3F80, 0x3F80, 0x3F80, 0x3F80, 0x3F80};
    const bf16x8 ones = __builtin_bit_cast(bf16x8, onesu);

    for (int half = 0; half < 2; half++) {
        const int qt = (half == 0) ? pair : (NT - 1 - pair);
        const int q0 = qt * 64;
        const int qrow = q0 + wid * 16 + li;
        const bf16x8 qa0 = *reinterpret_cast<const bf16x8*>(&QKV[baseQ + (size_t)qrow * HD3 + lg * 8]);
        const bf16x8 qa1 = *reinterpret_cast<const bf16x8*>(&QKV[baseQ + (size_t)qrow * HD3 + 32 + lg * 8]);
        const int myrow0 = q0 + wid * 16 + lg * 4;

        f32x4 acc[4] = {};
        f32x4 accl = {};
        int cur = 0;

        auto stage = [&](int k0s, int buf) {
#pragma unroll
            for (int i = 0; i < 2; i++)
                gload_lds16(&QKV[baseK + (size_t)(k0s + wid * 16 + i * 8 + srow) * HD3 + sgc],
                            &Kl[buf][wid * 16 + i * 8][0]);
#pragma unroll
            for (int i = 0; i < 2; i++) {
                const int lkey = 8 * wid + srow + 32 * i;
                const u16x8 vv = *reinterpret_cast<const u16x8*>(
                    &QKV[baseV + (size_t)(k0s + lkey) * HD3 + vx * 8]);
                const int vc = wid + 4 * i;
#pragma unroll
                for (int j = 0; j < 8; j++)
                    Vt[buf][vx * 8 + j][((vc ^ j ^ vx) & 7) * 8 + srow] = vv[j];
            }
        };

        __syncthreads();
        stage(0, 0);
        __syncthreads();

        auto tile_body = [&](int t, bool diag, bool pre) {
            const int k0 = t * 64;
            u16x8 vr0, vr1;
            if (pre) {
                const int kn = k0 + 64;
#pragma unroll
                for (int i = 0; i < 2; i++)
                    gload_lds16(&QKV[baseK + (size_t)(kn + wid * 16 + i * 8 + srow) * HD3 + sgc],
                                &Kl[cur ^ 1][wid * 16 + i * 8][0]);
                vr0 = *reinterpret_cast<const u16x8*>(
                    &QKV[baseV + (size_t)(kn + 8 * wid + srow) * HD3 + vx * 8]);
                vr1 = *reinterpret_cast<const u16x8*>(
                    &QKV[baseV + (size_t)(kn + 8 * wid + srow + 32) * HD3 + vx * 8]);
            }

            f32x4 s[4] = {};
            __builtin_amdgcn_s_setprio(1);
#pragma unroll
            for (int n = 0; n < 4; n++) {
                const int row = n * 16 + li;
                const bf16x8 kb0 = *reinterpret_cast<const bf16x8*>(
                    &Kl[cur][row][(lg ^ (li & 7)) * 8]);
                const bf16x8 kb1 = *reinterpret_cast<const bf16x8*>(
                    &Kl[cur][row][((4 + lg) ^ (li & 7)) * 8]);
                s[n] = __builtin_amdgcn_mfma_f32_16x16x32_bf16(qa0, kb0, s[n], 0, 0, 0);
                s[n] = __builtin_amdgcn_mfma_f32_16x16x32_bf16(qa1, kb1, s[n], 0, 0, 0);
            }
            __builtin_amdgcn_s_setprio(0);

#pragma unroll
            for (int n = 0; n < 4; n++) {
#pragma unroll
                for (int r = 0; r < 4; r++) {
                    float pv = fexp2(s[n][r]);
                    if (diag) {
                        const int key = k0 + n * 16 + li;
                        if (key > myrow0 + r) pv = 0.0f;
                    }
                    Pl[wid * 16 + lg * 4 + r][((2 * n + (li >> 3) + 2 * lg) & 7) * 8 + (li & 7)] = f2bf(pv);
                }
            }

            if (pre) {
#pragma unroll
                for (int j = 0; j < 8; j++)
                    Vt[cur ^ 1][vx * 8 + j][((wid ^ j ^ vx) & 7) * 8 + srow] = vr0[j];
#pragma unroll
                for (int j = 0; j < 8; j++)
                    Vt[cur ^ 1][vx * 8 + j][(((wid + 4) ^ j ^ vx) & 7) * 8 + srow] = vr1[j];
            }

            __builtin_amdgcn_s_setprio(1);
#pragma unroll
            for (int ks = 0; ks < 2; ks++) {
                const bf16x8 pa = *reinterpret_cast<const bf16x8*>(
                    &Pl[wid * 16 + li][((ks * 4 + lg + 2 * (li >> 2)) & 7) * 8]);
#pragma unroll
                for (int n = 0; n < 4; n++) {
                    const int row = n * 16 + li;
                    const bf16x8 vb = *reinterpret_cast<const bf16x8*>(
                        &Vt[cur][row][(((ks * 4 + lg) ^ (row & 7) ^ (row >> 3)) & 7) * 8]);
                    acc[n] = __builtin_amdgcn_mfma_f32_16x16x32_bf16(pa, vb, acc[n], 0, 0, 0);
                }
                accl = __builtin_amdgcn_mfma_f32_16x16x32_bf16(pa, ones, accl, 0, 0, 0);
            }
            __builtin_amdgcn_s_setprio(0);

            __syncthreads();
            cur ^= 1;
        };

        for (int t = 0; t < qt; t++) tile_body(t, false, true);
        tile_body(qt, true, false);

#pragma unroll
        for (int r = 0; r < 4; r++) {
            const float inv = 1.0f / accl[r];
            const int row = myrow0 + r;
#pragma unroll
            for (int n = 0; n < 4; n++)
                O[baseO + (size_t)row * HD + n * 16 + li] = f2bf(acc[n][r] * inv);
        }
    }
}

// ---------------- launch ----------------
extern "C" void kernel_launch(void* const* d_in, const int* in_sizes, int n_in,
                              void* d_out, int out_size, void* d_ws, size_t ws_size,
                              hipStream_t stream) {
    constexpr int B = 4, C = 2048, E = 1024, H = 16, FF = 4096;
    constexpr int M = B * C;  // 8192

    const float* x     = (const float*)d_in[0];
    const float* ln1_g = (const float*)d_in[1];
    const float* ln1_b = (const float*)d_in[2];
    const float* Wq    = (const float*)d_in[3];
    const float* Wk    = (const float*)d_in[4];
    const float* Wv    = (const float*)d_in[5];
    const float* Wo    = (const float*)d_in[6];
    const float* ln2_g = (const float*)d_in[7];
    const float* ln2_b = (const float*)d_in[8];
    const float* W1    = (const float*)d_in[9];
    const float* b1    = (const float*)d_in[10];
    const float* W2    = (const float*)d_in[11];
    const float* b2    = (const float*)d_in[12];

    char* p = (char*)d_ws;
    auto alloc = [&](size_t bytes) { void* r = (void*)p; p += (bytes + 255) & ~(size_t)255; return r; };
    unsigned short* WqT  = (unsigned short*)alloc((size_t)E * E * 2);   // Wq/Wk/Wv/Wo contiguous
    unsigned short* WkT  = (unsigned short*)alloc((size_t)E * E * 2);
    unsigned short* WvT  = (unsigned short*)alloc((size_t)E * E * 2);
    unsigned short* WoT  = (unsigned short*)alloc((size_t)E * E * 2);
    unsigned short* W1T  = (unsigned short*)alloc((size_t)E * FF * 2);
    unsigned short* W2T  = (unsigned short*)alloc((size_t)FF * E * 2);
    unsigned short* hb   = (unsigned short*)alloc((size_t)M * E * 2);
    unsigned short* QKVb = (unsigned short*)alloc((size_t)M * 3 * E * 2);
    unsigned short* attn = (unsigned short*)alloc((size_t)M * E * 2);
    float*          x1   = (float*)alloc((size_t)M * E * 4);
    unsigned short* h2   = (unsigned short*)alloc((size_t)M * E * 2);
    unsigned short* ff   = (unsigned short*)alloc((size_t)M * FF * 2);
    (void)WkT; (void)WvT;

    // weight conversion / transpose
    convT4_kernel<<<dim3(E / 32, E / 32, 4), 256, 0, stream>>>(Wq, Wk, Wv, Wo, WqT);
    convT_kernel<<<dim3(FF / 32, E / 32), 256, 0, stream>>>(W1, W1T, E, FF);
    convT_kernel<<<dim3(E / 32, FF / 32), 256, 0, stream>>>(W2, W2T, FF, E);

    // LN1
    ln_kernel<<<M, 256, 0, stream>>>(x, ln1_g, ln1_b, hb);

    // fused QKV projection (N=3072), Q columns pre-scaled; 8-phase 256^2, grid 384
    gemm_qkv<<<dim3(384), 512, 0, stream>>>(hb, WqT, nullptr, QKVb);

    // attention (r13 proven: QBLK=64, 4 waves, 1024 blocks)
    flash_kernel<<<dim3(1024), 256, 0, stream>>>(QKVb, attn);

    // output projection + residual; also writes d_out = x1 + b2 (base for W2's atomicAdd)
    gemm128_kernel<<<dim3(E / 128, M / 128), 256, 0, stream>>>(
        attn, WoT, x, b2, x1, (float*)d_out, M, E, E);

    // LN2
    ln_kernel<<<M, 256, 0, stream>>>(x1, ln2_g, ln2_b, h2);

    // FFN up + GELU (8-phase 256^2, grid 512)
    gemm_w1<<<dim3(512), 512, 0, stream>>>(h2, W1T, b1, ff);

    // FFN down: split-K=2 (grid 256), fp32 atomicAdd into pre-initialized d_out
    gemm_w2a<<<dim3(256), 512, 0, stream>>>(ff, W2T, nullptr, (float*)d_out);
}

// Round 16
// 346.548 us; speedup vs baseline: 1.2865x; 1.1345x over previous
//
#include <hip/hip_runtime.h>

typedef __bf16 bf16x8 __attribute__((ext_vector_type(8)));
typedef float f32x4 __attribute__((ext_vector_type(4)));
typedef unsigned short u16x8 __attribute__((ext_vector_type(8)));
typedef unsigned short u16x4 __attribute__((ext_vector_type(4)));

__device__ __forceinline__ unsigned short f2bf(float f) {
    return __builtin_bit_cast(unsigned short, (__bf16)f);  // v_cvt RNE
}
__device__ __forceinline__ float bf2f(unsigned short u) {
    return (float)__builtin_bit_cast(__bf16, u);
}

__device__ __forceinline__ float fexp2(float x) {
#if __has_builtin(__builtin_amdgcn_exp2f)
    return __builtin_amdgcn_exp2f(x);
#else
    float r; asm("v_exp_f32 %0, %1\n\ts_nop 1" : "=v"(r) : "v"(x)); return r;
#endif
}

__device__ __forceinline__ void gload_lds16(const unsigned short* g, unsigned short* l) {
    __builtin_amdgcn_global_load_lds(
        (const __attribute__((address_space(1))) unsigned int*)g,
        (__attribute__((address_space(3))) unsigned int*)l, 16, 0, 0);
}

#define VMW(n) asm volatile("s_waitcnt vmcnt(" #n ")" ::: "memory")
#define SBAR() __builtin_amdgcn_s_barrier()
#define SCHED0() __builtin_amdgcn_sched_barrier(0)

// Q pre-scale: 1/sqrt(64) * log2(e), folded into the QKV GEMM epilogue (Q cols only)
#define QSCALE 0.18033688011112042f

// ---------------- LayerNorm (LN1): fp32 in -> bf16 out (E=1024, one row per block) ----------
__global__ __launch_bounds__(256) void ln_kernel(
    const float* __restrict__ x, const float* __restrict__ g,
    const float* __restrict__ b, unsigned short* __restrict__ out)
{
    const int row = blockIdx.x;
    const int tid = threadIdx.x;
    const float4 v = reinterpret_cast<const float4*>(x + (size_t)row * 1024)[tid];
    float s = v.x + v.y + v.z + v.w;
    float q = v.x * v.x + v.y * v.y + v.z * v.z + v.w * v.w;
#pragma unroll
    for (int off = 32; off >= 1; off >>= 1) {
        s += __shfl_xor(s, off);
        q += __shfl_xor(q, off);
    }
    __shared__ float ss[4], sq[4];
    const int wid = tid >> 6, lane = tid & 63;
    if (lane == 0) { ss[wid] = s; sq[wid] = q; }
    __syncthreads();
    s = ss[0] + ss[1] + ss[2] + ss[3];
    q = sq[0] + sq[1] + sq[2] + sq[3];
    const float mu = s * (1.0f / 1024.0f);
    const float var = q * (1.0f / 1024.0f) - mu * mu;
    const float rs = rsqrtf(var + 1e-5f);
    const float4 gv = reinterpret_cast<const float4*>(g)[tid];
    const float4 bv = reinterpret_cast<const float4*>(b)[tid];
    u16x4 o;
    o[0] = f2bf((v.x - mu) * rs * gv.x + bv.x);
    o[1] = f2bf((v.y - mu) * rs * gv.y + bv.y);
    o[2] = f2bf((v.z - mu) * rs * gv.z + bv.z);
    o[3] = f2bf((v.w - mu) * rs * gv.w + bv.w);
    reinterpret_cast<u16x4*>(out + (size_t)row * 1024)[tid] = o;
}

// ---------------- LayerNorm (LN2): bf16 in -> bf16 out ----------------
__global__ __launch_bounds__(256) void ln_bf16_kernel(
    const unsigned short* __restrict__ x, const float* __restrict__ g,
    const float* __restrict__ b, unsigned short* __restrict__ out)
{
    const int row = blockIdx.x;
    const int tid = threadIdx.x;
    const u16x4 v4 = reinterpret_cast<const u16x4*>(x + (size_t)row * 1024)[tid];
    const float v0 = bf2f(v4[0]), v1 = bf2f(v4[1]), v2 = bf2f(v4[2]), v3 = bf2f(v4[3]);
    float s = v0 + v1 + v2 + v3;
    float q = v0 * v0 + v1 * v1 + v2 * v2 + v3 * v3;
#pragma unroll
    for (int off = 32; off >= 1; off >>= 1) {
        s += __shfl_xor(s, off);
        q += __shfl_xor(q, off);
    }
    __shared__ float ss[4], sq[4];
    const int wid = tid >> 6, lane = tid & 63;
    if (lane == 0) { ss[wid] = s; sq[wid] = q; }
    __syncthreads();
    s = ss[0] + ss[1] + ss[2] + ss[3];
    q = sq[0] + sq[1] + sq[2] + sq[3];
    const float mu = s * (1.0f / 1024.0f);
    const float var = q * (1.0f / 1024.0f) - mu * mu;
    const float rs = rsqrtf(var + 1e-5f);
    const float4 gv = reinterpret_cast<const float4*>(g)[tid];
    const float4 bv = reinterpret_cast<const float4*>(b)[tid];
    u16x4 o;
    o[0] = f2bf((v0 - mu) * rs * gv.x + bv.x);
    o[1] = f2bf((v1 - mu) * rs * gv.y + bv.y);
    o[2] = f2bf((v2 - mu) * rs * gv.z + bv.z);
    o[3] = f2bf((v3 - mu) * rs * gv.w + bv.w);
    reinterpret_cast<u16x4*>(out + (size_t)row * 1024)[tid] = o;
}

// 4 square E x E transposes in one dispatch (z picks the matrix; dsts contiguous)
__global__ __launch_bounds__(256) void convT4_kernel(
    const float* __restrict__ A0, const float* __restrict__ A1,
    const float* __restrict__ A2, const float* __restrict__ A3,
    unsigned short* __restrict__ Wt)
{
    constexpr int E = 1024;
    const int z = blockIdx.z;
    const float* W = (z == 0) ? A0 : (z == 1) ? A1 : (z == 2) ? A2 : A3;
    unsigned short* dst = Wt + (size_t)z * E * E;
    __shared__ float t[32][33];
    const int n0 = blockIdx.x * 32, k0 = blockIdx.y * 32;
    const int tx = threadIdx.x & 31;
    const int ty = threadIdx.x >> 5;
#pragma unroll
    for (int i = 0; i < 4; i++)
        t[ty + 8 * i][tx] = W[(size_t)(k0 + ty + 8 * i) * E + (n0 + tx)];
    __syncthreads();
#pragma unroll
    for (int i = 0; i < 4; i++)
        dst[(size_t)(n0 + ty + 8 * i) * E + (k0 + tx)] = f2bf(t[tx][ty + 8 * i]);
}

// W1 (1024x4096) and W2 (4096x1024) transposes in one dispatch (z picks)
__global__ __launch_bounds__(256) void convT2_kernel(
    const float* __restrict__ W1, unsigned short* __restrict__ W1T,
    const float* __restrict__ W2, unsigned short* __restrict__ W2T)
{
    const int z = blockIdx.z;
    const float* W = (z == 0) ? W1 : W2;
    unsigned short* dst = (z == 0) ? W1T : W2T;
    const int K = (z == 0) ? 1024 : 4096;
    const int N = (z == 0) ? 4096 : 1024;
    const int n0 = ((z == 0) ? (int)blockIdx.x : (int)blockIdx.y) * 32;
    const int k0 = ((z == 0) ? (int)blockIdx.y : (int)blockIdx.x) * 32;
    __shared__ float t[32][33];
    const int tx = threadIdx.x & 31;
    const int ty = threadIdx.x >> 5;
#pragma unroll
    for (int i = 0; i < 4; i++)
        t[ty + 8 * i][tx] = W[(size_t)(k0 + ty + 8 * i) * N + (n0 + tx)];
    __syncthreads();
#pragma unroll
    for (int i = 0; i < 4; i++)
        dst[(size_t)(n0 + ty + 8 * i) * K + (k0 + tx)] = f2bf(t[tx][ty + 8 * i]);
}

// ---------------- 128x128 m97-structure GEMM (Wo): x1 (bf16) = acc + resid ------------
__global__ __launch_bounds__(256) void gemm128_kernel(
    const unsigned short* __restrict__ A, const unsigned short* __restrict__ Bt,
    const float* __restrict__ resid, unsigned short* __restrict__ out, int M, int N, int K)
{
    __shared__ unsigned short Al[128][64];
    __shared__ unsigned short Bl[128][64];
    const int tid = threadIdx.x;
    const int lane = tid & 63, wid = tid >> 6;
    const int wr = wid >> 1, wc = wid & 1;
    const int li = lane & 15, lg = lane >> 4;
    const int m0 = blockIdx.y * 128, n0 = blockIdx.x * 128;
    const int srow = lane >> 3;
    const int schunk = ((lane & 7) ^ srow) * 8;
    const unsigned short* Asrc = A + (size_t)(m0 + wid * 32 + srow) * K + schunk;
    const unsigned short* Bsrc = Bt + (size_t)(n0 + wid * 32 + srow) * K + schunk;
    f32x4 acc[4][4] = {};

    for (int k0 = 0; k0 < K; k0 += 64) {
        __syncthreads();
#pragma unroll
        for (int i = 0; i < 4; i++) {
            gload_lds16(Asrc + k0 + (size_t)i * 8 * K, &Al[wid * 32 + i * 8][0]);
            gload_lds16(Bsrc + k0 + (size_t)i * 8 * K, &Bl[wid * 32 + i * 8][0]);
        }
        __syncthreads();
#pragma unroll
        for (int ks = 0; ks < 2; ks++) {
            bf16x8 af[4], bfr[4];
#pragma unroll
            for (int m = 0; m < 4; m++)
                af[m] = *reinterpret_cast<const bf16x8*>(
                    &Al[wr * 64 + m * 16 + li][((ks * 4 + lg) ^ (li & 7)) * 8]);
#pragma unroll
            for (int n = 0; n < 4; n++)
                bfr[n] = *reinterpret_cast<const bf16x8*>(
                    &Bl[wc * 64 + n * 16 + li][((ks * 4 + lg) ^ (li & 7)) * 8]);
#pragma unroll
            for (int m = 0; m < 4; m++)
#pragma unroll
                for (int n = 0; n < 4; n++)
                    acc[m][n] = __builtin_amdgcn_mfma_f32_16x16x32_bf16(af[m], bfr[n], acc[m][n], 0, 0, 0);
        }
    }

#pragma unroll
    for (int m = 0; m < 4; m++)
#pragma unroll
        for (int r = 0; r < 4; r++) {
            const int row = m0 + wr * 64 + m * 16 + lg * 4 + r;
#pragma unroll
            for (int n = 0; n < 4; n++) {
                const int col = n0 + wc * 64 + n * 16 + li;
                out[(size_t)row * N + col] = f2bf(acc[m][n][r] + resid[(size_t)row * N + col]);
            }
        }
}

// ---------------- 256x256 8-phase GEMM body (T1+T2+T3+T4+T5), stamped per-use -----------
// Separate kernel symbols + constexpr dims (rule #19 isolation, proven r13: W1 85µs/34%).
// EPI 2: bf16 gelu(acc+bias); EPI 4: bf16 raw partial (split-K); EPI 5: bf16 QKV.
#define DEFINE_GEMM256(NAME, EPI, SPLITK, MM, NN, KK)                                        \
__global__ __launch_bounds__(512, 2) void NAME(                                              \
    const unsigned short* __restrict__ A, const unsigned short* __restrict__ Bt,             \
    const float* __restrict__ bias, void* __restrict__ out)                                  \
{                                                                                            \
    constexpr int M = MM, N = NN, K = KK;                                                    \
    constexpr int GRID = SPLITK * (M >> 8) * (N >> 8);                                       \
    constexpr int nblk = (M >> 8) * (N >> 8);                                                \
    constexpr int cpx = GRID >> 3;                                                           \
    constexpr int nx = N >> 8;                                                               \
    constexpr int kLen = (SPLITK == 2) ? (K >> 1) : K;                                       \
    constexpr int NI = kLen >> 7;                                                            \
    __shared__ __align__(16) unsigned short Al[2][256][64];                                  \
    __shared__ __align__(16) unsigned short Bl[2][256][64];                                  \
    const int tid = threadIdx.x;                                                             \
    const int lane = tid & 63, wid = tid >> 6;                                               \
    const int wr = wid >> 2, wc = wid & 3;                                                   \
    const int li = lane & 15, lg = lane >> 4;                                                \
    const int swz = ((int)blockIdx.x & 7) * cpx + ((int)blockIdx.x >> 3);                    \
    int tsw = swz, sid = 0;                                                                  \
    if (SPLITK == 2) { sid = (swz >= nblk) ? 1 : 0; tsw = swz - sid * nblk; }                \
    const int bx = tsw % nx, by = tsw / nx;                                                  \
    const int m0 = by * 256, n0 = bx * 256;                                                  \
    const int kOff = (SPLITK == 2) ? sid * (K >> 1) : 0;                                     \
    const int srow = lane >> 3;                                                              \
    const int sgc = ((lane & 7) ^ srow) * 8;                                                 \
    const unsigned short* aSrc = A + (size_t)(m0 + wid * 16 + srow) * K + kOff + sgc;        \
    const unsigned short* bSrc = Bt + (size_t)(n0 + wid * 16 + srow) * K + kOff + sgc;       \
    unsigned short* aDst = &Al[0][wid * 16][0];                                              \
    unsigned short* bDst = &Bl[0][wid * 16][0];                                              \
    auto stA = [&](int u, int h) {                                                           \
        const unsigned short* s = aSrc + (size_t)(h * 128) * K + u * 64;                     \
        unsigned short* d = aDst + (u & 1) * (256 * 64) + h * 128 * 64;                      \
        gload_lds16(s, d);                                                                   \
        gload_lds16(s + (size_t)8 * K, d + 8 * 64);                                          \
    };                                                                                       \
    auto stB = [&](int u, int h) {                                                           \
        const unsigned short* s = bSrc + (size_t)(h * 128) * K + u * 64;                     \
        unsigned short* d = bDst + (u & 1) * (256 * 64) + h * 128 * 64;                      \
        gload_lds16(s, d);                                                                   \
        gload_lds16(s + (size_t)8 * K, d + 8 * 64);                                          \
    };                                                                                       \
    f32x4 acc[8][4] = {};                                                                    \
    bf16x8 af[8], bn0[4], bn1[4];                                                            \
    auto ldA = [&](int buf, int mh) {                                                        \
        _Pragma("unroll")                                                                    \
        for (int m = 0; m < 4; m++)                                                          \
            _Pragma("unroll")                                                                \
            for (int ks = 0; ks < 2; ks++)                                                   \
                af[m * 2 + ks] = *reinterpret_cast<const bf16x8*>(                           \
                    &Al[buf][wr * 128 + mh * 64 + m * 16 + li][((ks * 4 + lg) ^ (li & 7)) * 8]); \
    };                                                                                       \
    auto ldB = [&](bf16x8* dst, int buf, int nh) {                                           \
        _Pragma("unroll")                                                                    \
        for (int n = 0; n < 2; n++)                                                          \
            _Pragma("unroll")                                                                \
            for (int ks = 0; ks < 2; ks++)                                                   \
                dst[n * 2 + ks] = *reinterpret_cast<const bf16x8*>(                          \
                    &Bl[buf][wc * 64 + nh * 32 + n * 16 + li][((ks * 4 + lg) ^ (li & 7)) * 8]); \
    };                                                                                       \
    auto quad = [&](const bf16x8* bfr, int mh, int nh) {                                     \
        __builtin_amdgcn_s_setprio(1);                                                       \
        _Pragma("unroll")                                                                    \
        for (int ks = 0; ks < 2; ks++)                                                       \
            _Pragma("unroll")                                                                \
            for (int m = 0; m < 4; m++)                                                      \
                _Pragma("unroll")                                                            \
                for (int n = 0; n < 2; n++)                                                  \
                    acc[mh * 4 + m][nh * 2 + n] = __builtin_amdgcn_mfma_f32_16x16x32_bf16(   \
                        af[m * 2 + ks], bfr[n * 2 + ks], acc[mh * 4 + m][nh * 2 + n], 0, 0, 0); \
        __builtin_amdgcn_s_setprio(0);                                                       \
    };                                                                                       \
    stA(0, 0); stA(0, 1); stB(0, 0); stB(0, 1);                                              \
    stB(1, 0); stB(1, 1);                                                                    \
    VMW(4);                                                                                  \
    SBAR(); SCHED0();                                                                        \
    for (int I = 0; I < NI; ++I) {                                                           \
        const int u0 = 2 * I;                                                                \
        const bool hn = (I + 1 < NI);                                                        \
        ldA(0, 0); ldB(bn0, 0, 0);                                                           \
        stA(u0 + 1, 0);                                                                      \
        SBAR(); SCHED0();                                                                    \
        quad(bn0, 0, 0);                                                                     \
        SBAR(); SCHED0();                                                                    \
        ldB(bn1, 0, 1);                                                                      \
        stA(u0 + 1, 1);                                                                      \
        SBAR(); SCHED0();                                                                    \
        quad(bn1, 0, 1);                                                                     \
        SBAR(); SCHED0();                                                                    \
        ldA(0, 1);                                                                           \
        if (hn) stB(u0 + 2, 0);                                                              \
        SBAR(); SCHED0();                                                                    \
        quad(bn1, 1, 1);                                                                     \
        SBAR(); SCHED0();                                                                    \
        if (hn) stB(u0 + 2, 1);                                                              \
        SBAR(); SCHED0();                                                                    \
        quad(bn0, 1, 0);                                                                     \
        if (hn) { VMW(4); } else { VMW(0); }                                                 \
        SBAR(); SCHED0();                                                                    \
        ldA(1, 0); ldB(bn0, 1, 0);                                                           \
        if (hn) stA(u0 + 2, 0);                                                              \
        SBAR(); SCHED0();                                                                    \
        quad(bn0, 0, 0);                                                                     \
        SBAR(); SCHED0();                                                                    \
        ldB(bn1, 1, 1);                                                                      \
        if (hn) stA(u0 + 2, 1);                                                              \
        SBAR(); SCHED0();                                                                    \
        quad(bn1, 0, 1);                                                                     \
        SBAR(); SCHED0();                                                                    \
        ldA(1, 1);                                                                           \
        if (hn) stB(u0 + 3, 0);                                                              \
        SBAR(); SCHED0();                                                                    \
        quad(bn1, 1, 1);                                                                     \
        SBAR(); SCHED0();                                                                    \
        if (hn) stB(u0 + 3, 1);                                                              \
        SBAR(); SCHED0();                                                                    \
        quad(bn0, 1, 0);                                                                     \
        if (hn) { VMW(4); } else { VMW(0); }                                                 \
        SBAR(); SCHED0();                                                                    \
    }                                                                                        \
    _Pragma("unroll")                                                                        \
    for (int ma = 0; ma < 8; ma++) {                                                         \
        _Pragma("unroll")                                                                    \
        for (int r = 0; r < 4; r++) {                                                        \
            const int row = m0 + wr * 128 + ma * 16 + lg * 4 + r;                            \
            _Pragma("unroll")                                                                \
            for (int n = 0; n < 4; n++) {                                                    \
                const int col = n0 + wc * 64 + n * 16 + li;                                  \
                float v = acc[ma][n][r];                                                     \
                if constexpr (EPI == 2) {                                                    \
                    v += bias[col];                                                          \
                    float a2 = 1.5957691216f * (v + 0.044715f * v * v * v);                  \
                    a2 = fminf(a2, 80.0f);                                                   \
                    const float t = __expf(a2);                                              \
                    v = v * t * __builtin_amdgcn_rcpf(t + 1.0f);                             \
                    reinterpret_cast<unsigned short*>(out)[(size_t)row * N + col] = f2bf(v); \
                } else if constexpr (EPI == 4) {                                             \
                    unsigned short* op = reinterpret_cast<unsigned short*>(out) + (size_t)sid * M * N; \
                    op[(size_t)row * N + col] = f2bf(v);                                     \
                } else {                                                                     \
                    const float sc = (col < 1024) ? QSCALE : 1.0f;                           \
                    reinterpret_cast<unsigned short*>(out)[(size_t)row * N + col] = f2bf(v * sc); \
                }                                                                            \
            }                                                                                \
        }                                                                                    \
    }                                                                                        \
}

DEFINE_GEMM256(gemm_qkv, 5, 1, 8192, 3072, 1024)   // grid 384
DEFINE_GEMM256(gemm_w1,  2, 1, 8192, 4096, 1024)   // grid 512
DEFINE_GEMM256(gemm_w2,  4, 2, 8192, 1024, 4096)   // grid 256 (split-K=2)

// ------------- W2 split-K reduce: d_out = p0 + p1 + b2 + x1  (bf16 partials, bf16 x1) --------
__global__ __launch_bounds__(256) void w2red_kernel(
    const unsigned short* __restrict__ p0, const unsigned short* __restrict__ p1,
    const unsigned short* __restrict__ x1, const float* __restrict__ b2,
    float* __restrict__ out)
{
    const int i = blockIdx.x * 256 + threadIdx.x;     // 8-element index
    const u16x8 a = reinterpret_cast<const u16x8*>(p0)[i];
    const u16x8 b = reinterpret_cast<const u16x8*>(p1)[i];
    const u16x8 r = reinterpret_cast<const u16x8*>(x1)[i];
    const int cb = (i & 127) * 8;                     // col base within E=1024
    const float4 bb0 = *reinterpret_cast<const float4*>(b2 + cb);
    const float4 bb1 = *reinterpret_cast<const float4*>(b2 + cb + 4);
    float4 o0, o1;
    o0.x = bf2f(a[0]) + bf2f(b[0]) + bf2f(r[0]) + bb0.x;
    o0.y = bf2f(a[1]) + bf2f(b[1]) + bf2f(r[1]) + bb0.y;
    o0.z = bf2f(a[2]) + bf2f(b[2]) + bf2f(r[2]) + bb0.z;
    o0.w = bf2f(a[3]) + bf2f(b[3]) + bf2f(r[3]) + bb0.w;
    o1.x = bf2f(a[4]) + bf2f(b[4]) + bf2f(r[4]) + bb1.x;
    o1.y = bf2f(a[5]) + bf2f(b[5]) + bf2f(r[5]) + bb1.y;
    o1.z = bf2f(a[6]) + bf2f(b[6]) + bf2f(r[6]) + bb1.z;
    o1.w = bf2f(a[7]) + bf2f(b[7]) + bf2f(r[7]) + bb1.w;
    reinterpret_cast<float4*>(out)[2 * i] = o0;
    reinterpret_cast<float4*>(out)[2 * i + 1] = o1;
}

// ---------------- Flash attention (causal), r13 proven version (85µs) ----------------
// QKV [8192][3072] (Q pre-scaled by QSCALE). grid 1024 = 4 blocks/CU exactly resident.
__global__ __launch_bounds__(256, 4) void flash_kernel(
    const unsigned short* __restrict__ QKV, unsigned short* __restrict__ O)
{
    constexpr int C = 2048, HD3 = 3072, HD = 1024, NT = 32;
    __shared__ unsigned short Kl[2][64][64];  // [key][d], chunk XOR (row&7)
    __shared__ unsigned short Vt[2][64][64];  // [d][key], chunk XOR
    __shared__ unsigned short Pl[64][64];     // [q][key], chunk rotation
    const int tid = threadIdx.x;
    const int lane = tid & 63, wid = tid >> 6;
    const int li = lane & 15, lg = lane >> 4;
    const int flat = blockIdx.x;
    const int bh = flat & 63;
    const int pair = flat >> 6;
    const int b = bh >> 4, h = bh & 15;
    const size_t baseQ = ((size_t)b * C) * HD3 + (size_t)h * 64;
    const size_t baseK = baseQ + 1024;
    const size_t baseV = baseQ + 2048;
    const size_t baseO = ((size_t)b * C) * HD + (size_t)h * 64;

    const int srow = lane >> 3;
    const int sgc = ((lane & 7) ^ srow) * 8;
    const int vx = lane & 7;

    const u16x8 onesu = {0x3F80, 0x3F80, 0x3F80, 0x3F80, 0x3F80, 0x3F80, 0x3F80, 0x3F80};
    const bf16x8 ones = __builtin_bit_cast(bf16x8, onesu);

    for (int half = 0; half < 2; half++) {
        const int qt = (half == 0) ? pair : (NT - 1 - pair);
        const int q0 = qt * 64;
        const int qrow = q0 + wid * 16 + li;
        const bf16x8 qa0 = *reinterpret_cast<const bf16x8*>(&QKV[baseQ + (size_t)qrow * HD3 + lg * 8]);
        const bf16x8 qa1 = *reinterpret_cast<const bf16x8*>(&QKV[baseQ + (size_t)qrow * HD3 + 32 + lg * 8]);
        const int myrow0 = q0 + wid * 16 + lg * 4;

        f32x4 acc[4] = {};
        f32x4 accl = {};
        int cur = 0;

        auto stage = [&](int k0s, int buf) {
#pragma unroll
            for (int i = 0; i < 2; i++)
                gload_lds16(&QKV[baseK + (size_t)(k0s + wid * 16 + i * 8 + srow) * HD3 + sgc],
                            &Kl[buf][wid * 16 + i * 8][0]);
#pragma unroll
            for (int i = 0; i < 2; i++) {
                const int lkey = 8 * wid + srow + 32 * i;
                const u16x8 vv = *reinterpret_cast<const u16x8*>(
                    &QKV[baseV + (size_t)(k0s + lkey) * HD3 + vx * 8]);
                const int vc = wid + 4 * i;
#pragma unroll
                for (int j = 0; j < 8; j++)
                    Vt[buf][vx * 8 + j][((vc ^ j ^ vx) & 7) * 8 + srow] = vv[j];
            }
        };

        __syncthreads();
        stage(0, 0);
        __syncthreads();

        auto tile_body = [&](int t, bool diag, bool pre) {
            const int k0 = t * 64;
            u16x8 vr0, vr1;
            if (pre) {
                const int kn = k0 + 64;
#pragma unroll
                for (int i = 0; i < 2; i++)
                    gload_lds16(&QKV[baseK + (size_t)(kn + wid * 16 + i * 8 + srow) * HD3 + sgc],
                                &Kl[cur ^ 1][wid * 16 + i * 8][0]);
                vr0 = *reinterpret_cast<const u16x8*>(
                    &QKV[baseV + (size_t)(kn + 8 * wid + srow) * HD3 + vx * 8]);
                vr1 = *reinterpret_cast<const u16x8*>(
                    &QKV[baseV + (size_t)(kn + 8 * wid + srow + 32) * HD3 + vx * 8]);
            }

            f32x4 s[4] = {};
            __builtin_amdgcn_s_setprio(1);
#pragma unroll
            for (int n = 0; n < 4; n++) {
                const int row = n * 16 + li;
                const bf16x8 kb0 = *reinterpret_cast<const bf16x8*>(
                    &Kl[cur][row][(lg ^ (li & 7)) * 8]);
                const bf16x8 kb1 = *reinterpret_cast<const bf16x8*>(
                    &Kl[cur][row][((4 + lg) ^ (li & 7)) * 8]);
                s[n] = __builtin_amdgcn_mfma_f32_16x16x32_bf16(qa0, kb0, s[n], 0, 0, 0);
                s[n] = __builtin_amdgcn_mfma_f32_16x16x32_bf16(qa1, kb1, s[n], 0, 0, 0);
            }
            __builtin_amdgcn_s_setprio(0);

#pragma unroll
            for (int n = 0; n < 4; n++) {
#pragma unroll
                for (int r = 0; r < 4; r++) {
                    float pv = fexp2(s[n][r]);
                    if (diag) {
                        const int key = k0 + n * 16 + li;
                        if (key > myrow0 + r) pv = 0.0f;
                    }
                    Pl[wid * 16 + lg * 4 + r][((2 * n + (li >> 3) + 2 * lg) & 7) * 8 + (li & 7)] = f2bf(pv);
                }
            }

            if (pre) {
#pragma unroll
                for (int j = 0; j < 8; j++)
                    Vt[cur ^ 1][vx * 8 + j][((wid ^ j ^ vx) & 7) * 8 + srow] = vr0[j];
#pragma unroll
                for (int j = 0; j < 8; j++)
                    Vt[cur ^ 1][vx * 8 + j][(((wid + 4) ^ j ^ vx) & 7) * 8 + srow] = vr1[j];
            }

            __builtin_amdgcn_s_setprio(1);
#pragma unroll
            for (int ks = 0; ks < 2; ks++) {
                const bf16x8 pa = *reinterpret_cast<const bf16x8*>(
                    &Pl[wid * 16 + li][((ks * 4 + lg + 2 * (li >> 2)) & 7) * 8]);
#pragma unroll
                for (int n = 0; n < 4; n++) {
                    const int row = n * 16 + li;
                    const bf16x8 vb = *reinterpret_cast<const bf16x8*>(
                        &Vt[cur][row][(((ks * 4 + lg) ^ (row & 7) ^ (row >> 3)) & 7) * 8]);
                    acc[n] = __builtin_amdgcn_mfma_f32_16x16x32_bf16(pa, vb, acc[n], 0, 0, 0);
                }
                accl = __builtin_amdgcn_mfma_f32_16x16x32_bf16(pa, ones, accl, 0, 0, 0);
            }
            __builtin_amdgcn_s_setprio(0);

            __syncthreads();
            cur ^= 1;
        };

        for (int t = 0; t < qt; t++) tile_body(t, false, true);
        tile_body(qt, true, false);

#pragma unroll
        for (int r = 0; r < 4; r++) {
            const float inv = 1.0f / accl[r];
            const int row = myrow0 + r;
#pragma unroll
            for (int n = 0; n < 4; n++)
                O[baseO + (size_t)row * HD + n * 16 + li] = f2bf(acc[n][r] * inv);
        }
    }
}

// ---------------- launch ----------------
extern "C" void kernel_launch(void* const* d_in, const int* in_sizes, int n_in,
                              void* d_out, int out_size, void* d_ws, size_t ws_size,
                              hipStream_t stream) {
    constexpr int B = 4, C = 2048, E = 1024, H = 16, FF = 4096;
    constexpr int M = B * C;  // 8192

    const float* x     = (const float*)d_in[0];
    const float* ln1_g = (const float*)d_in[1];
    const float* ln1_b = (const float*)d_in[2];
    const float* Wq    = (const float*)d_in[3];
    const float* Wk    = (const float*)d_in[4];
    const float* Wv    = (const float*)d_in[5];
    const float* Wo    = (const float*)d_in[6];
    const float* ln2_g = (const float*)d_in[7];
    const float* ln2_b = (const float*)d_in[8];
    const float* W1    = (const float*)d_in[9];
    const float* b1    = (const float*)d_in[10];
    const float* W2    = (const float*)d_in[11];
    const float* b2    = (const float*)d_in[12];

    char* p = (char*)d_ws;
    auto alloc = [&](size_t bytes) { void* r = (void*)p; p += (bytes + 255) & ~(size_t)255; return r; };
    unsigned short* WqT  = (unsigned short*)alloc((size_t)E * E * 2);   // Wq/Wk/Wv/Wo contiguous
    unsigned short* WkT  = (unsigned short*)alloc((size_t)E * E * 2);
    unsigned short* WvT  = (unsigned short*)alloc((size_t)E * E * 2);
    unsigned short* WoT  = (unsigned short*)alloc((size_t)E * E * 2);
    unsigned short* W1T  = (unsigned short*)alloc((size_t)E * FF * 2);
    unsigned short* W2T  = (unsigned short*)alloc((size_t)FF * E * 2);
    unsigned short* hb   = (unsigned short*)alloc((size_t)M * E * 2);   // reused as W2 partials
    unsigned short* QKVb = (unsigned short*)alloc((size_t)M * 3 * E * 2);
    unsigned short* attn = (unsigned short*)alloc((size_t)M * E * 2);
    unsigned short* x1   = (unsigned short*)alloc((size_t)M * E * 2);   // bf16 residual stream
    unsigned short* h2   = (unsigned short*)alloc((size_t)M * E * 2);
    unsigned short* ff   = (unsigned short*)alloc((size_t)M * FF * 2);
    (void)WkT; (void)WvT;
    unsigned short* parts = hb;  // 2 x 16MB bf16 partials: spans hb+QKVb (both dead by then)

    // weight conversion / transpose
    convT4_kernel<<<dim3(E / 32, E / 32, 4), 256, 0, stream>>>(Wq, Wk, Wv, Wo, WqT);
    convT2_kernel<<<dim3(FF / 32, E / 32, 2), 256, 0, stream>>>(W1, W1T, W2, W2T);

    // LN1
    ln_kernel<<<M, 256, 0, stream>>>(x, ln1_g, ln1_b, hb);

    // fused QKV projection (N=3072), Q columns pre-scaled; 8-phase 256^2, grid 384
    gemm_qkv<<<dim3(384), 512, 0, stream>>>(hb, WqT, nullptr, QKVb);

    // attention (r13 proven: QBLK=64, 4 waves, 1024 blocks)
    flash_kernel<<<dim3(1024), 256, 0, stream>>>(QKVb, attn);

    // output projection + residual -> bf16 x1 (m97 128^2, grid 512 = 2/CU)
    gemm128_kernel<<<dim3(E / 128, M / 128), 256, 0, stream>>>(
        attn, WoT, x, x1, M, E, E);

    // LN2 (bf16 input)
    ln_bf16_kernel<<<M, 256, 0, stream>>>(x1, ln2_g, ln2_b, h2);

    // FFN up + GELU (8-phase 256^2, grid 512)
    gemm_w1<<<dim3(512), 512, 0, stream>>>(h2, W1T, b1, ff);

    // FFN down: split-K=2 (grid 256 = full machine), bf16 partials, then reduce
    gemm_w2<<<dim3(256), 512, 0, stream>>>(ff, W2T, nullptr, parts);
    w2red_kernel<<<dim3(M * E / 8 / 256), 256, 0, stream>>>(
        parts, parts + (size_t)M * E, x1, b2, (float*)d_out);
}